// Round 16
// baseline (123.823 us; speedup 1.0000x reference)
//
#include <hip/hip_runtime.h>

// Problem constants
#define NB    16
#define TLEN  1024
#define CCH   128
#define DR    320

typedef _Float16 h8 __attribute__((ext_vector_type(8)));
typedef _Float16 h4 __attribute__((ext_vector_type(4)));
typedef _Float16 h2 __attribute__((ext_vector_type(2)));
typedef float    f4 __attribute__((ext_vector_type(4)));

// async global->LDS, 16 B/lane. LDS dest = readfirstlane(base)+lane*16, LINEAR.
__device__ __forceinline__ void gload16h(const _Float16* g, _Float16* l) {
  __builtin_amdgcn_global_load_lds(
      (const __attribute__((address_space(1))) void*)g,
      (__attribute__((address_space(3))) void*)l, 16, 0, 0);
}
__device__ __forceinline__ void gload16f(const float* g, float* l) {
  __builtin_amdgcn_global_load_lds(
      (const __attribute__((address_space(1))) void*)g,
      (__attribute__((address_space(3))) void*)l, 16, 0, 0);
}

// ---------------------------------------------------------------------------
// Init: cast x->h0 (f16), weight prep, fblb2 = fb+lb. 1024 blocks. (verified)
__global__ __launch_bounds__(256) void k_init(const float* __restrict__ x,
                                              const float* __restrict__ w1,
                                              const float* __restrict__ w2,
                                              const float* __restrict__ linw,
                                              const float* __restrict__ fb,
                                              const float* __restrict__ lb,
                                              _Float16* __restrict__ h0,
                                              _Float16* __restrict__ Wsh,
                                              _Float16* __restrict__ linWh,
                                              float* __restrict__ fblb2) {
  int i = blockIdx.x * 256 + threadIdx.x;     // 0..262143
  const float4* src = (const float4*)x + (size_t)i * 2;
  float4 a = src[0], b = src[1];
  h8 v;
  v[0] = (_Float16)a.x; v[1] = (_Float16)a.y; v[2] = (_Float16)a.z; v[3] = (_Float16)a.w;
  v[4] = (_Float16)b.x; v[5] = (_Float16)b.y; v[6] = (_Float16)b.z; v[7] = (_Float16)b.w;
  *(h8*)(h0 + (size_t)i * 8) = v;

  if (i < 6 * 32768) {
    int c = i & 127, k = (i >> 7) & 1, o = (i >> 8) & 127, i3 = i >> 15;
    const float* srcw = (i3 < 3) ? (w1 + i3 * 32768) : (w2 + (i3 - 3) * 32768);
    Wsh[i] = (_Float16)srcw[(o * 128 + c) * 2 + k];
  }
  if (i < 16384) linWh[i] = (_Float16)linw[i];
  if (i < 98304) fblb2[i] = fb[i] + lb[i];
}

// ---------------------------------------------------------------------------
struct SGen {
  float buf[3][32 * DR];    // 122,880 B
  float csc[4][16][16];     // 4,096 B
  float fbl[512];           // 2,048 B   (total 129,024 B)
};
struct SPairC {             // pair-chain buffers (total 92 KB)
  _Float16 B0[128 * 128];   // 32 KB  in1 -> out2 -> in3
  _Float16 B1[128 * 128];   // 32 KB  a1/a2
  _Float16 B2[112 * 128];   // 28 KB  out1/in2 -> a3
};
union alignas(16) SU { SGen g; SPairC p; };

// ---------------------------------------------------------------------------
// gen body (verified r14): 192 blocks x 512 rows, 16 tiles; 3-buffer pipeline.
__device__ __forceinline__ void gen_body(SGen& S, int bid, int tid,
                                         const float* __restrict__ r,
                                         const float* __restrict__ fW,
                                         const float* __restrict__ fblb2,
                                         _Float16* __restrict__ wg) {
  constexpr int NT = 16;
  const size_t rbase = (size_t)bid * 512;

  const int l = tid & 63, w = tid >> 6;
  const int l15 = l & 15, lh = l >> 4;
  const int rt = w >> 1, kh = w & 1;

  f4 rx[5], ry[5];
  const float* rp = r + l15 * DR + kh * 160 + lh * 8;
#pragma unroll
  for (int cb = 0; cb < 5; cb++) {
    rx[cb] = *(const f4*)(rp + cb * 32);
    ry[cb] = *(const f4*)(rp + cb * 32 + 4);
  }
  if (tid < 128) gload16f(fblb2 + rbase + tid * 4, S.fbl + tid * 4);
#pragma unroll
  for (int t = 0; t < 3; t++) {
    const float* s = fW + (rbase + (size_t)t * 32) * DR;
#pragma unroll
    for (int i = 0; i < 10; i++) {
      int f = tid + i * 256;
      gload16f(s + (size_t)f * 4, (float*)S.buf[t] + (size_t)f * 4);
    }
  }
  h8 bfr[5];
#pragma unroll
  for (int cb = 0; cb < 5; cb++) {
    h8 v;
    v[0] = (_Float16)rx[cb][0]; v[1] = (_Float16)rx[cb][1];
    v[2] = (_Float16)rx[cb][2]; v[3] = (_Float16)rx[cb][3];
    v[4] = (_Float16)ry[cb][0]; v[5] = (_Float16)ry[cb][1];
    v[6] = (_Float16)ry[cb][2]; v[7] = (_Float16)ry[cb][3];
    bfr[cb] = v;
  }
  asm volatile("s_waitcnt vmcnt(20) lgkmcnt(0)" ::: "memory");
  __builtin_amdgcn_s_barrier();
  __builtin_amdgcn_sched_barrier(0);

  const int rn = tid >> 4, rk = (tid >> 3) & 1, rcq = tid & 7;

  for (int j = 0; j < NT; j++) {
    const float* bp = (const float*)S.buf[j % 3];
    f4 acc = {0.f, 0.f, 0.f, 0.f};
    const float* arow = bp + (rt * 16 + l15) * DR + kh * 160 + lh * 8;
#pragma unroll
    for (int cb = 0; cb < 5; cb++) {
      f4 x = *(const f4*)(arow + cb * 32);
      f4 y = *(const f4*)(arow + cb * 32 + 4);
      h8 a;
      a[0] = (_Float16)x[0]; a[1] = (_Float16)x[1];
      a[2] = (_Float16)x[2]; a[3] = (_Float16)x[3];
      a[4] = (_Float16)y[0]; a[5] = (_Float16)y[1];
      a[6] = (_Float16)y[2]; a[7] = (_Float16)y[3];
      acc = __builtin_amdgcn_mfma_f32_16x16x32_f16(a, bfr[cb], acc, 0, 0, 0);
    }
#pragma unroll
    for (int rr = 0; rr < 4; rr++) S.csc[w][lh * 4 + rr][l15] = acc[rr];

    asm volatile("s_waitcnt lgkmcnt(0)" ::: "memory");
    __builtin_amdgcn_s_barrier();
    __builtin_amdgcn_sched_barrier(0);

    {
      const unsigned g32 = (unsigned)(rbase + (size_t)j * 32);
      const unsigned G = g32 >> 15, o = (g32 >> 8) & 127u, c0 = (g32 & 255u) >> 1;
      h2 v2;
#pragma unroll
      for (int i = 0; i < 2; i++) {
        int rl32 = (rcq * 2 + i) * 2 + rk;
        int hp = (rl32 >> 4) * 2, rr2 = rl32 & 15;
        float s = S.csc[hp][rr2][rn] + S.csc[hp + 1][rr2][rn] + S.fbl[j * 32 + rl32];
        v2[i] = (_Float16)s;
      }
      unsigned q = 3u * (unsigned)rn + G;
      *(h2*)&wg[(((size_t)q * 128 + o) * 2 + rk) * 128 + c0 + rcq * 2] = v2;
    }
    __builtin_amdgcn_sched_barrier(0);

    if (j + 3 < NT) {
      float* dstb = (float*)S.buf[j % 3];
      const float* src = fW + (rbase + (size_t)(j + 3) * 32) * DR;
#pragma unroll
      for (int i = 0; i < 10; i++) {
        int f = tid + i * 256;
        gload16f(src + (size_t)f * 4, dstb + (size_t)f * 4);
      }
    }

    if (j + 4 <= NT)
      asm volatile("s_waitcnt vmcnt(20) lgkmcnt(0)" ::: "memory");
    else if (j + 3 == NT)
      asm volatile("s_waitcnt vmcnt(10) lgkmcnt(0)" ::: "memory");
    else
      asm volatile("s_waitcnt vmcnt(0) lgkmcnt(0)" ::: "memory");
    __builtin_amdgcn_s_barrier();
    __builtin_amdgcn_sched_barrier(0);
  }
}

// ---------------------------------------------------------------------------
// Generalized pair stage on LDS (derived from verified pair_body):
// in rows p in [0,(NJ+1)*16): t = inB + p.  out rows r in [0,NJ*16):
// t = inB + 16 + r.  a rows q: t = inB + D + q (scratch, NJ+1 tiles).
// conv1: a[q] = relu(W1_0 in[q] + W1_1 in[q+D] + b1), zero q < zlimA.
// conv2: out[r] = relu(relu(W2_0 a[r+16-2D] + W2_1 a[r+16-D] + b2) + in[r+16]),
//        zero r < zlimO.  GOUT: write global h-tile [t0,t0+64) instead of LDS.
template <int D, int NJ, bool GOUT>
__device__ __forceinline__ void pstage(const _Float16* __restrict__ w1p,
                                       const _Float16* __restrict__ w2p,
                                       const float* __restrict__ b1p,
                                       const float* __restrict__ b2p,
                                       const _Float16* __restrict__ inb,
                                       _Float16* __restrict__ ab,
                                       _Float16* __restrict__ outb,
                                       _Float16* __restrict__ goutN, int t0,
                                       int zlimA, int zlimO, int tid) {
  constexpr int NA = NJ + 1;
  const int l = tid & 63, w = tid >> 6;
  const int l15 = l & 15, lh = l >> 4;
  const int o0 = w * 32;
  const int base8 = o0 + (lh >> 1) * 8;   // +i2*16 applied per i2
  const int sub = (lh & 1) * 4;

  // ---- conv1 -> a ----
  f4 acc1[2][NA] = {};
#pragma unroll
  for (int tap = 0; tap < 2; tap++) {
#pragma unroll
    for (int cb = 0; cb < 4; cb++) {
      const int c0 = cb * 32 + lh * 8;
      h8 a[2], bfr[NA];
#pragma unroll
      for (int i2 = 0; i2 < 2; i2++) {
        int o = o0 + i2 * 16 + l15;
        a[i2] = *(const h8*)&w1p[(o * 2 + tap) * 128 + c0];
      }
#pragma unroll
      for (int jt = 0; jt < NA; jt++) {
        int p = jt * 16 + l15 + tap * D;
        int cs = c0 ^ ((p & 15) << 3);
        bfr[jt] = *(const h8*)&inb[p * 128 + cs];
      }
#pragma unroll
      for (int i2 = 0; i2 < 2; i2++)
#pragma unroll
        for (int jt = 0; jt < NA; jt++)
          acc1[i2][jt] = __builtin_amdgcn_mfma_f32_16x16x32_f16(
              a[i2], bfr[jt], acc1[i2][jt], 0, 0, 0);
    }
  }
#pragma unroll
  for (int i2 = 0; i2 < 2; i2++) {
    f4 bv = *(const f4*)&b1p[o0 + i2 * 16 + lh * 4];
    const int b8 = base8 + i2 * 16;
#pragma unroll
    for (int jt = 0; jt < NA; jt++) {
      int q = jt * 16 + l15;
      h4 sv;
      if (q < zlimA) {
        sv[0] = sv[1] = sv[2] = sv[3] = (_Float16)0.f;
      } else {
        f4 v = acc1[i2][jt];
#pragma unroll
        for (int rr = 0; rr < 4; rr++) sv[rr] = (_Float16)fmaxf(v[rr] + bv[rr], 0.f);
      }
      *(h4*)&ab[q * 128 + (b8 ^ ((q & 15) << 3)) + sub] = sv;
    }
  }
  __syncthreads();

  // ---- conv2 + residual ----
  f4 acc2[2][NJ] = {};
#pragma unroll
  for (int tap = 0; tap < 2; tap++) {
#pragma unroll
    for (int cb = 0; cb < 4; cb++) {
      const int c0 = cb * 32 + lh * 8;
      h8 a[2], bfr[NJ];
#pragma unroll
      for (int i2 = 0; i2 < 2; i2++) {
        int o = o0 + i2 * 16 + l15;
        a[i2] = *(const h8*)&w2p[(o * 2 + tap) * 128 + c0];
      }
#pragma unroll
      for (int jt = 0; jt < NJ; jt++) {
        int pa = jt * 16 + l15 + (16 - 2 * D) + tap * D;
        int cs = c0 ^ ((pa & 15) << 3);
        bfr[jt] = *(const h8*)&ab[pa * 128 + cs];
      }
#pragma unroll
      for (int i2 = 0; i2 < 2; i2++)
#pragma unroll
        for (int jt = 0; jt < NJ; jt++)
          acc2[i2][jt] = __builtin_amdgcn_mfma_f32_16x16x32_f16(
              a[i2], bfr[jt], acc2[i2][jt], 0, 0, 0);
    }
  }
#pragma unroll
  for (int i2 = 0; i2 < 2; i2++) {
    f4 bv = *(const f4*)&b2p[o0 + i2 * 16 + lh * 4];
    const int b8 = base8 + i2 * 16;
#pragma unroll
    for (int jt = 0; jt < NJ; jt++) {
      int r = jt * 16 + l15;
      int pr = r + 16;
      h4 sv;
      if (r < zlimO) {
        sv[0] = sv[1] = sv[2] = sv[3] = (_Float16)0.f;
      } else {
        h4 rv = *(const h4*)&inb[pr * 128 + (b8 ^ ((pr & 15) << 3)) + sub];
        f4 v = acc2[i2][jt];
#pragma unroll
        for (int rr = 0; rr < 4; rr++) {
          float z = fmaxf(v[rr] + bv[rr], 0.f);
          sv[rr] = (_Float16)fmaxf(z + (float)rv[rr], 0.f);
        }
      }
      if (GOUT) {
        int t = t0 + r;
        *(h4*)&goutN[t * 128 + o0 + i2 * 16 + lh * 4] = sv;
      } else {
        *(h4*)&outb[r * 128 + (b8 ^ (l15 << 3)) + sub] = sv;
      }
    }
  }
}

// ---------------------------------------------------------------------------
// Fused gen || pair-chain: blocks 0..191 gen; blocks 192..255 each run the
// full shared-pair chain (p1 d=1 -> p2 d=2 -> p3 d=4) for 4 tiles, entirely
// in LDS via halo recompute. No cross-role or cross-block dependencies.
__global__ __launch_bounds__(256, 1) void k_genpair(
    const float* __restrict__ r, const float* __restrict__ fW,
    const float* __restrict__ fblb2, _Float16* __restrict__ wg,
    const _Float16* __restrict__ h0, _Float16* __restrict__ h1,
    const _Float16* __restrict__ Wsh,
    const float* __restrict__ b1, const float* __restrict__ b2) {
  __shared__ SU su;
  const int bid = blockIdx.x, tid = threadIdx.x;
  if (bid < 192) {
    gen_body(su.g, bid, tid, r, fW, fblb2, wg);
    return;
  }
  const int pb = bid - 192;   // 0..63
  for (int rep = 0; rep < 4; rep++) {
    const int q = pb + rep * 64;
    const int tx = q & 15, n = q >> 4;
    const int t0 = tx * 64;
    const _Float16* inN = h0 + (size_t)n * (TLEN * CCH);
    __syncthreads();   // previous rep's readers done before restaging B0

    // stage in1 = h0 rows [t0-48, t0+64), 112 rows (7 tiles) -> B0
    if (tx == 0) {
      for (int f = tid; f < 48 * 16; f += 256)
        *(int4*)(su.p.B0 + (size_t)f * 8) = make_int4(0, 0, 0, 0);
      for (int f = 48 * 16 + tid; f < 112 * 16; f += 256) {
        int p = f >> 4, l16 = f & 15;
        int c8 = (l16 ^ (p & 15)) << 3;
        gload16h(inN + (t0 - 48 + p) * 128 + c8, su.p.B0 + f * 8);
      }
    } else {
      for (int f = tid; f < 112 * 16; f += 256) {
        int p = f >> 4, l16 = f & 15;
        int c8 = (l16 ^ (p & 15)) << 3;
        gload16h(inN + (t0 - 48 + p) * 128 + c8, su.p.B0 + f * 8);
      }
    }
    __syncthreads();

    // p1 (d=1): in B0 [t0-48,+64) -> out B2 [t0-32,+64), a in B1
    pstage<1, 6, false>(Wsh, Wsh + 3 * 32768, b1, b2,
                        su.p.B0, su.p.B1, su.p.B2, nullptr, t0,
                        (tx == 0) ? 47 : 0, (tx == 0) ? 32 : 0, tid);
    __syncthreads();
    // p2 (d=2): in B2 [t0-32,+64) -> out B0 [t0-16,+64), a in B1
    pstage<2, 5, false>(Wsh + 1 * 32768, Wsh + 4 * 32768, b1 + 128, b2 + 128,
                        su.p.B2, su.p.B1, su.p.B0, nullptr, t0,
                        (tx == 0) ? 30 : 0, (tx == 0) ? 16 : 0, tid);
    __syncthreads();
    // p3 (d=4): in B0 [t0-16,+64) -> global h1 tile [t0,+64), a in B2
    pstage<4, 4, true>(Wsh + 2 * 32768, Wsh + 5 * 32768, b1 + 256, b2 + 256,
                       su.p.B0, su.p.B2, nullptr,
                       h1 + (size_t)n * (TLEN * CCH), t0,
                       (tx == 0) ? 12 : 0, 0, tid);
  }
}

// ---------------------------------------------------------------------------
// One group-conv stage on LDS buffers (verified r15).
template <int D, int NJ>
__device__ __forceinline__ void gstage(const _Float16* __restrict__ Wl,
                                       const _Float16* __restrict__ inb,
                                       _Float16* __restrict__ outb,
                                       int zlim, int tid) {
  const int l = tid & 63, w = tid >> 6;
  const int l15 = l & 15, lh = l >> 4;
  const int o0 = w * 32;
  f4 acc[2][NJ] = {};

#pragma unroll
  for (int tap = 0; tap < 2; tap++) {
#pragma unroll
    for (int cb = 0; cb < 4; cb++) {
      const int c0 = cb * 32 + 8 * lh;
      h8 a[2], bfr[NJ];
#pragma unroll
      for (int i2 = 0; i2 < 2; i2++) {
        int o = o0 + i2 * 16 + l15;
        int cs = c0 ^ ((o & 15) << 3);
        a[i2] = *(const h8*)&Wl[(o * 2 + tap) * 128 + cs];
      }
#pragma unroll
      for (int jt = 0; jt < NJ; jt++) {
        int p = jt * 16 + l15 + tap * D;
        int cs = c0 ^ ((p & 15) << 3);
        bfr[jt] = *(const h8*)&inb[p * 128 + cs];
      }
#pragma unroll
      for (int i2 = 0; i2 < 2; i2++)
#pragma unroll
        for (int jt = 0; jt < NJ; jt++)
          acc[i2][jt] = __builtin_amdgcn_mfma_f32_16x16x32_f16(
              a[i2], bfr[jt], acc[i2][jt], 0, 0, 0);
    }
  }

#pragma unroll
  for (int i2 = 0; i2 < 2; i2++) {
    const int base8 = o0 + i2 * 16 + (lh >> 1) * 8;
    const int sub = (lh & 1) * 4;
#pragma unroll
    for (int jt = 0; jt < NJ; jt++) {
      int rrow = jt * 16 + l15;
      int pr = rrow + D;
      h4 sv;
      if (rrow < zlim) {
        sv[0] = sv[1] = sv[2] = sv[3] = (_Float16)0.f;
      } else {
        h4 rv = *(const h4*)&inb[pr * 128 + (base8 ^ ((pr & 15) << 3)) + sub];
        f4 v = acc[i2][jt];
#pragma unroll
        for (int rr = 0; rr < 4; rr++) {
          float z = fmaxf(v[rr], 0.f);
          sv[rr] = (_Float16)fmaxf(z + (float)rv[rr], 0.f);
        }
      }
      *(h4*)&outb[rrow * 128 + (base8 ^ (l15 << 3)) + sub] = sv;
    }
  }
}

// ---------------------------------------------------------------------------
// Fused group chain (verified r15): conv8 -> conv16 -> conv32 -> linear.
__global__ __launch_bounds__(256, 1) void k_group(const _Float16* __restrict__ in,
                                                  float* __restrict__ outp,
                                                  const _Float16* __restrict__ wg,
                                                  const _Float16* __restrict__ linWh,
                                                  const float* __restrict__ lbias) {
  __shared__ _Float16 bufA[120 * 128];   // 30 KB: in1, then out2
  __shared__ _Float16 bufB[112 * 128];   // 28 KB: out1, then a_l
  __shared__ _Float16 Wl[256 * 128];     // 64 KB, reloaded per stage
  const int tid = threadIdx.x;
  const int tx = blockIdx.x, n = blockIdx.y;
  const int t0 = tx * 64;
  const _Float16* inN = in + (size_t)n * (TLEN * CCH);
  const _Float16* wp1 = wg + (size_t)n * 32768;
  const _Float16* wp2 = wg + 524288 + (size_t)n * 32768;
  const _Float16* wp3 = wg + 1048576 + (size_t)n * 32768;

  if (tx == 0) {
    for (int f = tid; f < 56 * 16; f += 256)
      *(int4*)(bufA + (size_t)f * 8) = make_int4(0, 0, 0, 0);
    for (int f = 56 * 16 + tid; f < 120 * 16; f += 256) {
      int p = f >> 4, l16 = f & 15;
      int c8 = (l16 ^ (p & 15)) << 3;
      gload16h(inN + (t0 - 56 + p) * 128 + c8, bufA + f * 8);
    }
  } else {
    for (int f = tid; f < 120 * 16; f += 256) {
      int p = f >> 4, l16 = f & 15;
      int c8 = (l16 ^ (p & 15)) << 3;
      gload16h(inN + (t0 - 56 + p) * 128 + c8, bufA + f * 8);
    }
  }
  for (int f = tid; f < 4096; f += 256) {
    int row = f >> 4, l16 = f & 15;
    int c8 = (l16 ^ ((row >> 1) & 15)) << 3;
    gload16h(wp1 + row * 128 + c8, Wl + f * 8);
  }
  __syncthreads();

  gstage<8, 7>(Wl, bufA, bufB, (tx == 0) ? 48 : 0, tid);
  __syncthreads();
  for (int f = tid; f < 4096; f += 256) {
    int row = f >> 4, l16 = f & 15;
    int c8 = (l16 ^ ((row >> 1) & 15)) << 3;
    gload16h(wp2 + row * 128 + c8, Wl + f * 8);
  }
  __syncthreads();

  gstage<16, 6>(Wl, bufB, bufA, (tx == 0) ? 32 : 0, tid);
  __syncthreads();
  for (int f = tid; f < 4096; f += 256) {
    int row = f >> 4, l16 = f & 15;
    int c8 = (l16 ^ ((row >> 1) & 15)) << 3;
    gload16h(wp3 + row * 128 + c8, Wl + f * 8);
  }
  __syncthreads();

  gstage<32, 4>(Wl, bufA, bufB, 0, tid);
  __syncthreads();

  const int l = tid & 63, w = tid >> 6;
  const int l15 = l & 15, lh = l >> 4;
  const int o0 = w * 32;
  f4 acc3[2][4] = {};
#pragma unroll
  for (int cb = 0; cb < 4; cb++) {
    const int c0 = cb * 32 + lh * 8;
    h8 a[2], bfr[4];
#pragma unroll
    for (int i2 = 0; i2 < 2; i2++) {
      int o = o0 + i2 * 16 + l15;
      a[i2] = *(const h8*)&linWh[o * 128 + c0];
    }
#pragma unroll
    for (int jt = 0; jt < 4; jt++) {
      int p = jt * 16 + l15;
      int cs = c0 ^ ((p & 15) << 3);
      bfr[jt] = *(const h8*)&bufB[p * 128 + cs];
    }
#pragma unroll
    for (int i2 = 0; i2 < 2; i2++)
#pragma unroll
      for (int jt = 0; jt < 4; jt++)
        acc3[i2][jt] = __builtin_amdgcn_mfma_f32_16x16x32_f16(
            a[i2], bfr[jt], acc3[i2][jt], 0, 0, 0);
  }

#pragma unroll
  for (int i2 = 0; i2 < 2; i2++) {
    int o = o0 + i2 * 16 + lh * 4;
    f4 bv = *(const f4*)&lbias[o];
#pragma unroll
    for (int jt = 0; jt < 4; jt++) {
      int t = t0 + jt * 16 + l15;
      f4 v = acc3[i2][jt];
      float4 sv = make_float4(v[0] + bv[0], v[1] + bv[1], v[2] + bv[2], v[3] + bv[3]);
      *(float4*)&outp[((size_t)n * TLEN + t) * CCH + o] = sv;
    }
  }
}

// ---------------------------------------------------------------------------
extern "C" void kernel_launch(void* const* d_in, const int* in_sizes, int n_in,
                              void* d_out, int out_size, void* d_ws, size_t ws_size,
                              hipStream_t stream) {
  const float* x  = (const float*)d_in[0];
  const float* r  = (const float*)d_in[1];
  // d_in[2] = f_out_same_in_size (==1)
  const float* w1 = (const float*)d_in[3];
  const float* b1 = (const float*)d_in[4];
  const float* w2 = (const float*)d_in[5];
  const float* b2 = (const float*)d_in[6];
  const float* fW = (const float*)d_in[7];
  const float* fb = (const float*)d_in[8];
  const float* lb = (const float*)d_in[9];
  const float* lw = (const float*)d_in[10];
  const float* lbias = (const float*)d_in[11];
  float* out = (float*)d_out;

  _Float16* h0    = (_Float16*)d_ws;        // 2,097,152 halves
  _Float16* h1    = h0 + 2097152;           // 2,097,152
  _Float16* Wsh   = h1 + 2097152;           // 393,216
  _Float16* linWh = Wsh + 393216;           // 16,384
  _Float16* Wg    = linWh + 16384;          // 1,572,864
  float*    fblb2 = (float*)(Wg + 1572864); // 98,304 floats

  k_init<<<1024, 256, 0, stream>>>(x, w1, w2, lw, fb, lb, h0, Wsh, linWh, fblb2);
  // gen (blocks 0..191) || full shared-pair chain (blocks 192..255)
  k_genpair<<<256, 256, 0, stream>>>(r, fW, fblb2, Wg, h0, h1, Wsh, b1, b2);
  // fused group chain: conv8 -> conv16 -> conv32 -> linear
  k_group<<<dim3(16, 16), 256, 0, stream>>>(h1, out, Wg, linWh, lbias);
}

// Round 18
// 72.782 us; speedup vs baseline: 1.7013x; 1.7013x over previous
//
#include <hip/hip_runtime.h>

// Problem constants
#define NB    16
#define TLEN  1024
#define CCH   128
#define DR    320

typedef _Float16 h8 __attribute__((ext_vector_type(8)));
typedef _Float16 h4 __attribute__((ext_vector_type(4)));
typedef _Float16 h2 __attribute__((ext_vector_type(2)));
typedef float    f4 __attribute__((ext_vector_type(4)));

// async global->LDS, 16 B/lane. LDS dest = readfirstlane(base)+lane*16, LINEAR.
__device__ __forceinline__ void gload16h(const _Float16* g, _Float16* l) {
  __builtin_amdgcn_global_load_lds(
      (const __attribute__((address_space(1))) void*)g,
      (__attribute__((address_space(3))) void*)l, 16, 0, 0);
}
__device__ __forceinline__ void gload16f(const float* g, float* l) {
  __builtin_amdgcn_global_load_lds(
      (const __attribute__((address_space(1))) void*)g,
      (__attribute__((address_space(3))) void*)l, 16, 0, 0);
}

// ---------------------------------------------------------------------------
// Init: cast x->h0 (f16), weight prep, fblb2 = fb+lb. (verified)
__global__ __launch_bounds__(256) void k_init(const float* __restrict__ x,
                                              const float* __restrict__ w1,
                                              const float* __restrict__ w2,
                                              const float* __restrict__ linw,
                                              const float* __restrict__ fb,
                                              const float* __restrict__ lb,
                                              _Float16* __restrict__ h0,
                                              _Float16* __restrict__ Wsh,
                                              _Float16* __restrict__ linWh,
                                              float* __restrict__ fblb2) {
  int i = blockIdx.x * 256 + threadIdx.x;     // 0..262143
  const float4* src = (const float4*)x + (size_t)i * 2;
  float4 a = src[0], b = src[1];
  h8 v;
  v[0] = (_Float16)a.x; v[1] = (_Float16)a.y; v[2] = (_Float16)a.z; v[3] = (_Float16)a.w;
  v[4] = (_Float16)b.x; v[5] = (_Float16)b.y; v[6] = (_Float16)b.z; v[7] = (_Float16)b.w;
  *(h8*)(h0 + (size_t)i * 8) = v;

  if (i < 6 * 32768) {
    int c = i & 127, k = (i >> 7) & 1, o = (i >> 8) & 127, i3 = i >> 15;
    const float* srcw = (i3 < 3) ? (w1 + i3 * 32768) : (w2 + (i3 - 3) * 32768);
    Wsh[i] = (_Float16)srcw[(o * 128 + c) * 2 + k];
  }
  if (i < 16384) linWh[i] = (_Float16)linw[i];
  if (i < 98304) fblb2[i] = fb[i] + lb[i];
}

// ---------------------------------------------------------------------------
struct SGen {
  float buf[3][32 * DR];    // 122,880 B
  float csc[4][16][16];     // 4,096 B
  float fbl[512];           // 2,048 B
};
struct SPair {              // sized for the LARGEST D used (D=4: RIN=84)
  _Float16 hin[84 * 128];
  _Float16 a[80 * 128];
};
union alignas(16) SU { SGen g; SPair p; };

// ---------------------------------------------------------------------------
// gen body — byte-exact r14/r15 version (post-timing verified twice).
__device__ __forceinline__ void gen_body(SGen& S, int bid, int tid,
                                         const float* __restrict__ r,
                                         const float* __restrict__ fW,
                                         const float* __restrict__ fblb2,
                                         _Float16* __restrict__ wg) {
  constexpr int NT = 16;
  const size_t rbase = (size_t)bid * 512;

  const int l = tid & 63, w = tid >> 6;
  const int l15 = l & 15, lh = l >> 4;
  const int rt = w >> 1, kh = w & 1;

  f4 rx[5], ry[5];
  const float* rp = r + l15 * DR + kh * 160 + lh * 8;
#pragma unroll
  for (int cb = 0; cb < 5; cb++) {
    rx[cb] = *(const f4*)(rp + cb * 32);
    ry[cb] = *(const f4*)(rp + cb * 32 + 4);
  }
  if (tid < 128) gload16f(fblb2 + rbase + tid * 4, S.fbl + tid * 4);
#pragma unroll
  for (int t = 0; t < 3; t++) {
    const float* s = fW + (rbase + (size_t)t * 32) * DR;
#pragma unroll
    for (int i = 0; i < 10; i++) {
      int f = tid + i * 256;
      gload16f(s + (size_t)f * 4, (float*)S.buf[t] + (size_t)f * 4);
    }
  }
  h8 bfr[5];
#pragma unroll
  for (int cb = 0; cb < 5; cb++) {
    h8 v;
    v[0] = (_Float16)rx[cb][0]; v[1] = (_Float16)rx[cb][1];
    v[2] = (_Float16)rx[cb][2]; v[3] = (_Float16)rx[cb][3];
    v[4] = (_Float16)ry[cb][0]; v[5] = (_Float16)ry[cb][1];
    v[6] = (_Float16)ry[cb][2]; v[7] = (_Float16)ry[cb][3];
    bfr[cb] = v;
  }
  asm volatile("s_waitcnt vmcnt(20) lgkmcnt(0)" ::: "memory");
  __builtin_amdgcn_s_barrier();
  __builtin_amdgcn_sched_barrier(0);

  const int rn = tid >> 4, rk = (tid >> 3) & 1, rcq = tid & 7;

  for (int j = 0; j < NT; j++) {
    const float* bp = (const float*)S.buf[j % 3];
    f4 acc = {0.f, 0.f, 0.f, 0.f};
    const float* arow = bp + (rt * 16 + l15) * DR + kh * 160 + lh * 8;
#pragma unroll
    for (int cb = 0; cb < 5; cb++) {
      f4 x = *(const f4*)(arow + cb * 32);
      f4 y = *(const f4*)(arow + cb * 32 + 4);
      h8 a;
      a[0] = (_Float16)x[0]; a[1] = (_Float16)x[1];
      a[2] = (_Float16)x[2]; a[3] = (_Float16)x[3];
      a[4] = (_Float16)y[0]; a[5] = (_Float16)y[1];
      a[6] = (_Float16)y[2]; a[7] = (_Float16)y[3];
      acc = __builtin_amdgcn_mfma_f32_16x16x32_f16(a, bfr[cb], acc, 0, 0, 0);
    }
#pragma unroll
    for (int rr = 0; rr < 4; rr++) S.csc[w][lh * 4 + rr][l15] = acc[rr];

    asm volatile("s_waitcnt lgkmcnt(0)" ::: "memory");
    __builtin_amdgcn_s_barrier();
    __builtin_amdgcn_sched_barrier(0);

    {
      const unsigned g32 = (unsigned)(rbase + (size_t)j * 32);
      const unsigned G = g32 >> 15, o = (g32 >> 8) & 127u, c0 = (g32 & 255u) >> 1;
      h2 v2;
#pragma unroll
      for (int i = 0; i < 2; i++) {
        int rl32 = (rcq * 2 + i) * 2 + rk;
        int hp = (rl32 >> 4) * 2, rr2 = rl32 & 15;
        float s = S.csc[hp][rr2][rn] + S.csc[hp + 1][rr2][rn] + S.fbl[j * 32 + rl32];
        v2[i] = (_Float16)s;
      }
      unsigned q = 3u * (unsigned)rn + G;
      *(h2*)&wg[(((size_t)q * 128 + o) * 2 + rk) * 128 + c0 + rcq * 2] = v2;
    }
    __builtin_amdgcn_sched_barrier(0);

    if (j + 3 < NT) {
      float* dstb = (float*)S.buf[j % 3];
      const float* src = fW + (rbase + (size_t)(j + 3) * 32) * DR;
#pragma unroll
      for (int i = 0; i < 10; i++) {
        int f = tid + i * 256;
        gload16f(src + (size_t)f * 4, dstb + (size_t)f * 4);
      }
    }

    if (j + 4 <= NT)
      asm volatile("s_waitcnt vmcnt(20) lgkmcnt(0)" ::: "memory");
    else if (j + 3 == NT)
      asm volatile("s_waitcnt vmcnt(10) lgkmcnt(0)" ::: "memory");
    else
      asm volatile("s_waitcnt vmcnt(0) lgkmcnt(0)" ::: "memory");
    __builtin_amdgcn_s_barrier();
    __builtin_amdgcn_sched_barrier(0);
  }
}

// ---------------------------------------------------------------------------
// pair body (verified r14/r15), on (tx, n).
template <int D>
__device__ __forceinline__ void pair_body(SPair& S, int tx, int n, int tid,
                                          const _Float16* in, _Float16* out,
                                          const _Float16* w1p, const _Float16* w2p,
                                          const float* b1p, const float* b2p) {
  constexpr int HA = 16;
  constexpr int HI = HA + D;
  constexpr int RIN = 80 + D;
  static_assert(RIN * 128 <= sizeof(SPair::hin) / sizeof(_Float16), "hin size");
  _Float16* hin_l = S.hin;
  _Float16* a_l = S.a;
  const int t0 = tx * 64;
  const _Float16* inN = in + (size_t)n * (TLEN * CCH);

  if (tx == 0) {
    for (int f = tid; f < HI * 16; f += 256)
      *(int4*)(hin_l + (size_t)f * 8) = make_int4(0, 0, 0, 0);
    for (int f = HI * 16 + tid; f < RIN * 16; f += 256) {
      int p = f >> 4, l16 = f & 15;
      int c8 = (l16 ^ (p & 15)) << 3;
      gload16h(inN + (t0 - HI + p) * 128 + c8, hin_l + f * 8);
    }
  } else {
    for (int f = tid; f < RIN * 16; f += 256) {
      int p = f >> 4, l16 = f & 15;
      int c8 = (l16 ^ (p & 15)) << 3;
      gload16h(inN + (t0 - HI + p) * 128 + c8, hin_l + f * 8);
    }
  }
  __syncthreads();

  const int l = tid & 63, w = tid >> 6;
  const int l15 = l & 15, lh = l >> 4;
  const int o0 = w * 32;

  f4 acc1[2][5] = {};
#pragma unroll
  for (int tap = 0; tap < 2; tap++) {
#pragma unroll
    for (int cb = 0; cb < 4; cb++) {
      const int c0 = cb * 32 + lh * 8;
      h8 a[2], bfr[5];
#pragma unroll
      for (int i2 = 0; i2 < 2; i2++) {
        int o = o0 + i2 * 16 + l15;
        a[i2] = *(const h8*)&w1p[(o * 2 + tap) * 128 + c0];
      }
#pragma unroll
      for (int jt = 0; jt < 5; jt++) {
        int p = jt * 16 + l15 + tap * D;
        int cs = c0 ^ ((p & 15) << 3);
        bfr[jt] = *(const h8*)&hin_l[p * 128 + cs];
      }
#pragma unroll
      for (int i2 = 0; i2 < 2; i2++)
#pragma unroll
        for (int jt = 0; jt < 5; jt++)
          acc1[i2][jt] = __builtin_amdgcn_mfma_f32_16x16x32_f16(
              a[i2], bfr[jt], acc1[i2][jt], 0, 0, 0);
    }
  }
#pragma unroll
  for (int i2 = 0; i2 < 2; i2++) {
    f4 bv = *(const f4*)&b1p[o0 + i2 * 16 + lh * 4];
    const int base8 = o0 + i2 * 16 + (lh >> 1) * 8;
    const int sub = (lh & 1) * 4;
#pragma unroll
    for (int jt = 0; jt < 5; jt++) {
      int p = jt * 16 + l15;
      h4 sv;
      if (tx == 0 && jt == 0) {
        sv[0] = sv[1] = sv[2] = sv[3] = (_Float16)0.f;
      } else {
        f4 v = acc1[i2][jt];
#pragma unroll
        for (int rr = 0; rr < 4; rr++) sv[rr] = (_Float16)fmaxf(v[rr] + bv[rr], 0.f);
      }
      *(h4*)&a_l[p * 128 + (base8 ^ ((p & 15) << 3)) + sub] = sv;
    }
  }
  __syncthreads();

  f4 acc2[2][4] = {};
#pragma unroll
  for (int tap = 0; tap < 2; tap++) {
#pragma unroll
    for (int cb = 0; cb < 4; cb++) {
      const int c0 = cb * 32 + lh * 8;
      h8 a[2], bfr[4];
#pragma unroll
      for (int i2 = 0; i2 < 2; i2++) {
        int o = o0 + i2 * 16 + l15;
        a[i2] = *(const h8*)&w2p[(o * 2 + tap) * 128 + c0];
      }
#pragma unroll
      for (int jt = 0; jt < 4; jt++) {
        int pa = jt * 16 + l15 + (HA - D) + tap * D;
        int cs = c0 ^ ((pa & 15) << 3);
        bfr[jt] = *(const h8*)&a_l[pa * 128 + cs];
      }
#pragma unroll
      for (int i2 = 0; i2 < 2; i2++)
#pragma unroll
        for (int jt = 0; jt < 4; jt++)
          acc2[i2][jt] = __builtin_amdgcn_mfma_f32_16x16x32_f16(
              a[i2], bfr[jt], acc2[i2][jt], 0, 0, 0);
    }
  }

  _Float16* outN = out + (size_t)n * (TLEN * CCH);
#pragma unroll
  for (int i2 = 0; i2 < 2; i2++) {
    f4 bv = *(const f4*)&b2p[o0 + i2 * 16 + lh * 4];
    const int base8 = o0 + i2 * 16 + (lh >> 1) * 8;
    const int sub = (lh & 1) * 4;
#pragma unroll
    for (int jt = 0; jt < 4; jt++) {
      int t = t0 + jt * 16 + l15;
      int pr = jt * 16 + l15 + HA + D;
      h4 rv = *(const h4*)&hin_l[pr * 128 + (base8 ^ ((pr & 15) << 3)) + sub];
      f4 v = acc2[i2][jt];
      h4 sv;
#pragma unroll
      for (int rr = 0; rr < 4; rr++) {
        float z = fmaxf(v[rr] + bv[rr], 0.f);
        sv[rr] = (_Float16)fmaxf(z + (float)rv[rr], 0.f);
      }
      *(h4*)&outN[t * 128 + o0 + i2 * 16 + lh * 4] = sv;
    }
  }
}

// ---------------------------------------------------------------------------
// Fused gen || pair1 (r15 structure, post-timing verified): grid 448.
__global__ __launch_bounds__(256, 1) void k_genpair(
    const float* __restrict__ r, const float* __restrict__ fW,
    const float* __restrict__ fblb2, _Float16* __restrict__ wg,
    const _Float16* __restrict__ h0, _Float16* __restrict__ h1,
    const _Float16* __restrict__ Wsh,
    const float* __restrict__ b1, const float* __restrict__ b2) {
  __shared__ SU su;
  const int bid = blockIdx.x, tid = threadIdx.x;
  if (bid < 192) {
    gen_body(su.g, bid, tid, r, fW, fblb2, wg);
  } else {
    int q = bid - 192;
    pair_body<1>(su.p, q & 15, q >> 4, tid, h0, h1,
                 Wsh, Wsh + 3 * 32768, b1, b2);
  }
}

// ---------------------------------------------------------------------------
// Generalized pair stage on LDS (numerics verified r16/r17 first-call).
template <int D, int NJ, bool GOUT>
__device__ __forceinline__ void pstage(const _Float16* __restrict__ w1p,
                                       const _Float16* __restrict__ w2p,
                                       const float* __restrict__ b1p,
                                       const float* __restrict__ b2p,
                                       const _Float16* __restrict__ inb,
                                       _Float16* __restrict__ ab,
                                       _Float16* __restrict__ outb,
                                       _Float16* __restrict__ goutN, int t0,
                                       int zlimA, int zlimO, int tid) {
  constexpr int NA = NJ + 1;
  const int l = tid & 63, w = tid >> 6;
  const int l15 = l & 15, lh = l >> 4;
  const int o0 = w * 32;
  const int base8 = o0 + (lh >> 1) * 8;
  const int sub = (lh & 1) * 4;

  f4 acc1[2][NA] = {};
#pragma unroll
  for (int tap = 0; tap < 2; tap++) {
#pragma unroll
    for (int cb = 0; cb < 4; cb++) {
      const int c0 = cb * 32 + lh * 8;
      h8 a[2], bfr[NA];
#pragma unroll
      for (int i2 = 0; i2 < 2; i2++) {
        int o = o0 + i2 * 16 + l15;
        a[i2] = *(const h8*)&w1p[(o * 2 + tap) * 128 + c0];
      }
#pragma unroll
      for (int jt = 0; jt < NA; jt++) {
        int p = jt * 16 + l15 + tap * D;
        int cs = c0 ^ ((p & 15) << 3);
        bfr[jt] = *(const h8*)&inb[p * 128 + cs];
      }
#pragma unroll
      for (int i2 = 0; i2 < 2; i2++)
#pragma unroll
        for (int jt = 0; jt < NA; jt++)
          acc1[i2][jt] = __builtin_amdgcn_mfma_f32_16x16x32_f16(
              a[i2], bfr[jt], acc1[i2][jt], 0, 0, 0);
    }
  }
#pragma unroll
  for (int i2 = 0; i2 < 2; i2++) {
    f4 bv = *(const f4*)&b1p[o0 + i2 * 16 + lh * 4];
    const int b8 = base8 + i2 * 16;
#pragma unroll
    for (int jt = 0; jt < NA; jt++) {
      int q = jt * 16 + l15;
      h4 sv;
      if (q < zlimA) {
        sv[0] = sv[1] = sv[2] = sv[3] = (_Float16)0.f;
      } else {
        f4 v = acc1[i2][jt];
#pragma unroll
        for (int rr = 0; rr < 4; rr++) sv[rr] = (_Float16)fmaxf(v[rr] + bv[rr], 0.f);
      }
      *(h4*)&ab[q * 128 + (b8 ^ ((q & 15) << 3)) + sub] = sv;
    }
  }
  __syncthreads();

  f4 acc2[2][NJ] = {};
#pragma unroll
  for (int tap = 0; tap < 2; tap++) {
#pragma unroll
    for (int cb = 0; cb < 4; cb++) {
      const int c0 = cb * 32 + lh * 8;
      h8 a[2], bfr[NJ];
#pragma unroll
      for (int i2 = 0; i2 < 2; i2++) {
        int o = o0 + i2 * 16 + l15;
        a[i2] = *(const h8*)&w2p[(o * 2 + tap) * 128 + c0];
      }
#pragma unroll
      for (int jt = 0; jt < NJ; jt++) {
        int pa = jt * 16 + l15 + (16 - 2 * D) + tap * D;
        int cs = c0 ^ ((pa & 15) << 3);
        bfr[jt] = *(const h8*)&ab[pa * 128 + cs];
      }
#pragma unroll
      for (int i2 = 0; i2 < 2; i2++)
#pragma unroll
        for (int jt = 0; jt < NJ; jt++)
          acc2[i2][jt] = __builtin_amdgcn_mfma_f32_16x16x32_f16(
              a[i2], bfr[jt], acc2[i2][jt], 0, 0, 0);
    }
  }
#pragma unroll
  for (int i2 = 0; i2 < 2; i2++) {
    f4 bv = *(const f4*)&b2p[o0 + i2 * 16 + lh * 4];
    const int b8 = base8 + i2 * 16;
#pragma unroll
    for (int jt = 0; jt < NJ; jt++) {
      int r = jt * 16 + l15;
      int pr = r + 16;
      h4 sv;
      if (r < zlimO) {
        sv[0] = sv[1] = sv[2] = sv[3] = (_Float16)0.f;
      } else {
        h4 rv = *(const h4*)&inb[pr * 128 + (b8 ^ ((pr & 15) << 3)) + sub];
        f4 v = acc2[i2][jt];
#pragma unroll
        for (int rr = 0; rr < 4; rr++) {
          float z = fmaxf(v[rr] + bv[rr], 0.f);
          sv[rr] = (_Float16)fmaxf(z + (float)rv[rr], 0.f);
        }
      }
      if (GOUT) {
        int t = t0 + r;
        *(h4*)&goutN[t * 128 + o0 + i2 * 16 + lh * 4] = sv;
      } else {
        *(h4*)&outb[r * 128 + (b8 ^ (l15 << 3)) + sub] = sv;
      }
    }
  }
}

// ---------------------------------------------------------------------------
// Fused pair2 (d=2) + pair4 (d=4) via halo recompute. HARDENED: every LDS row
// that any read can touch is explicitly initialized (no uninit-read paths).
__global__ __launch_bounds__(256) void k_pair24(const _Float16* __restrict__ in,
                                                _Float16* __restrict__ out,
                                                const _Float16* __restrict__ Wsh,
                                                const float* __restrict__ b1,
                                                const float* __restrict__ b2) {
  __shared__ _Float16 B0[104 * 128];   // in: rows [t0-32, t0+64); tail zeroed
  __shared__ _Float16 B1[96 * 128];    // a scratch (fully written by conv1)
  __shared__ _Float16 B2[88 * 128];    // mid: rows [t0-16, t0+64); tail zeroed
  const int tid = threadIdx.x;
  const int tx = blockIdx.x, n = blockIdx.y;
  const int t0 = tx * 64;
  const _Float16* inN = in + (size_t)n * (TLEN * CCH);

  // zero tails read by conv1 halo over-reads: B0 rows 96..103, B2 rows 80..87
  for (int f = 96 * 16 + tid; f < 104 * 16; f += 256)
    *(int4*)(B0 + (size_t)f * 8) = make_int4(0, 0, 0, 0);
  for (int f = 80 * 16 + tid; f < 88 * 16; f += 256)
    *(int4*)(B2 + (size_t)f * 8) = make_int4(0, 0, 0, 0);

  if (tx == 0) {
    for (int f = tid; f < 32 * 16; f += 256)
      *(int4*)(B0 + (size_t)f * 8) = make_int4(0, 0, 0, 0);
    for (int f = 32 * 16 + tid; f < 96 * 16; f += 256) {
      int p = f >> 4, l16 = f & 15;
      int c8 = (l16 ^ (p & 15)) << 3;
      gload16h(inN + (t0 - 32 + p) * 128 + c8, B0 + f * 8);
    }
  } else {
    for (int f = tid; f < 96 * 16; f += 256) {
      int p = f >> 4, l16 = f & 15;
      int c8 = (l16 ^ (p & 15)) << 3;
      gload16h(inN + (t0 - 32 + p) * 128 + c8, B0 + f * 8);
    }
  }
  __syncthreads();

  // pair2 (d=2): B0 [t0-32,+64) -> B2 [t0-16,+64)
  pstage<2, 5, false>(Wsh + 1 * 32768, Wsh + 4 * 32768, b1 + 128, b2 + 128,
                      B0, B1, B2, nullptr, t0,
                      (tx == 0) ? 30 : 0, (tx == 0) ? 16 : 0, tid);
  __syncthreads();
  // pair4 (d=4): B2 [t0-16,+64) -> global out tile [t0,+64)
  pstage<4, 4, true>(Wsh + 2 * 32768, Wsh + 5 * 32768, b1 + 256, b2 + 256,
                     B2, B1, nullptr,
                     out + (size_t)n * (TLEN * CCH), t0,
                     (tx == 0) ? 12 : 0, 0, tid);
}

// ---------------------------------------------------------------------------
// One group-conv stage on LDS buffers (verified r15).
template <int D, int NJ>
__device__ __forceinline__ void gstage(const _Float16* __restrict__ Wl,
                                       const _Float16* __restrict__ inb,
                                       _Float16* __restrict__ outb,
                                       int zlim, int tid) {
  const int l = tid & 63, w = tid >> 6;
  const int l15 = l & 15, lh = l >> 4;
  const int o0 = w * 32;
  f4 acc[2][NJ] = {};

#pragma unroll
  for (int tap = 0; tap < 2; tap++) {
#pragma unroll
    for (int cb = 0; cb < 4; cb++) {
      const int c0 = cb * 32 + 8 * lh;
      h8 a[2], bfr[NJ];
#pragma unroll
      for (int i2 = 0; i2 < 2; i2++) {
        int o = o0 + i2 * 16 + l15;
        int cs = c0 ^ ((o & 15) << 3);
        a[i2] = *(const h8*)&Wl[(o * 2 + tap) * 128 + cs];
      }
#pragma unroll
      for (int jt = 0; jt < NJ; jt++) {
        int p = jt * 16 + l15 + tap * D;
        int cs = c0 ^ ((p & 15) << 3);
        bfr[jt] = *(const h8*)&inb[p * 128 + cs];
      }
#pragma unroll
      for (int i2 = 0; i2 < 2; i2++)
#pragma unroll
        for (int jt = 0; jt < NJ; jt++)
          acc[i2][jt] = __builtin_amdgcn_mfma_f32_16x16x32_f16(
              a[i2], bfr[jt], acc[i2][jt], 0, 0, 0);
    }
  }

#pragma unroll
  for (int i2 = 0; i2 < 2; i2++) {
    const int base8 = o0 + i2 * 16 + (lh >> 1) * 8;
    const int sub = (lh & 1) * 4;
#pragma unroll
    for (int jt = 0; jt < NJ; jt++) {
      int rrow = jt * 16 + l15;
      int pr = rrow + D;
      h4 sv;
      if (rrow < zlim) {
        sv[0] = sv[1] = sv[2] = sv[3] = (_Float16)0.f;
      } else {
        h4 rv = *(const h4*)&inb[pr * 128 + (base8 ^ ((pr & 15) << 3)) + sub];
        f4 v = acc[i2][jt];
#pragma unroll
        for (int rr = 0; rr < 4; rr++) {
          float z = fmaxf(v[rr], 0.f);
          sv[rr] = (_Float16)fmaxf(z + (float)rv[rr], 0.f);
        }
      }
      *(h4*)&outb[rrow * 128 + (base8 ^ (l15 << 3)) + sub] = sv;
    }
  }
}

// ---------------------------------------------------------------------------
// Fused group chain (verified r15): conv8 -> conv16 -> conv32 -> linear.
__global__ __launch_bounds__(256, 1) void k_group(const _Float16* __restrict__ in,
                                                  float* __restrict__ outp,
                                                  const _Float16* __restrict__ wg,
                                                  const _Float16* __restrict__ linWh,
                                                  const float* __restrict__ lbias) {
  __shared__ _Float16 bufA[120 * 128];
  __shared__ _Float16 bufB[112 * 128];
  __shared__ _Float16 Wl[256 * 128];
  const int tid = threadIdx.x;
  const int tx = blockIdx.x, n = blockIdx.y;
  const int t0 = tx * 64;
  const _Float16* inN = in + (size_t)n * (TLEN * CCH);
  const _Float16* wp1 = wg + (size_t)n * 32768;
  const _Float16* wp2 = wg + 524288 + (size_t)n * 32768;
  const _Float16* wp3 = wg + 1048576 + (size_t)n * 32768;

  if (tx == 0) {
    for (int f = tid; f < 56 * 16; f += 256)
      *(int4*)(bufA + (size_t)f * 8) = make_int4(0, 0, 0, 0);
    for (int f = 56 * 16 + tid; f < 120 * 16; f += 256) {
      int p = f >> 4, l16 = f & 15;
      int c8 = (l16 ^ (p & 15)) << 3;
      gload16h(inN + (t0 - 56 + p) * 128 + c8, bufA + f * 8);
    }
  } else {
    for (int f = tid; f < 120 * 16; f += 256) {
      int p = f >> 4, l16 = f & 15;
      int c8 = (l16 ^ (p & 15)) << 3;
      gload16h(inN + (t0 - 56 + p) * 128 + c8, bufA + f * 8);
    }
  }
  for (int f = tid; f < 4096; f += 256) {
    int row = f >> 4, l16 = f & 15;
    int c8 = (l16 ^ ((row >> 1) & 15)) << 3;
    gload16h(wp1 + row * 128 + c8, Wl + f * 8);
  }
  __syncthreads();

  gstage<8, 7>(Wl, bufA, bufB, (tx == 0) ? 48 : 0, tid);
  __syncthreads();
  for (int f = tid; f < 4096; f += 256) {
    int row = f >> 4, l16 = f & 15;
    int c8 = (l16 ^ ((row >> 1) & 15)) << 3;
    gload16h(wp2 + row * 128 + c8, Wl + f * 8);
  }
  __syncthreads();

  gstage<16, 6>(Wl, bufB, bufA, (tx == 0) ? 32 : 0, tid);
  __syncthreads();
  for (int f = tid; f < 4096; f += 256) {
    int row = f >> 4, l16 = f & 15;
    int c8 = (l16 ^ ((row >> 1) & 15)) << 3;
    gload16h(wp3 + row * 128 + c8, Wl + f * 8);
  }
  __syncthreads();

  gstage<32, 4>(Wl, bufA, bufB, 0, tid);
  __syncthreads();

  const int l = tid & 63, w = tid >> 6;
  const int l15 = l & 15, lh = l >> 4;
  const int o0 = w * 32;
  f4 acc3[2][4] = {};
#pragma unroll
  for (int cb = 0; cb < 4; cb++) {
    const int c0 = cb * 32 + lh * 8;
    h8 a[2], bfr[4];
#pragma unroll
    for (int i2 = 0; i2 < 2; i2++) {
      int o = o0 + i2 * 16 + l15;
      a[i2] = *(const h8*)&linWh[o * 128 + c0];
    }
#pragma unroll
    for (int jt = 0; jt < 4; jt++) {
      int p = jt * 16 + l15;
      int cs = c0 ^ ((p & 15) << 3);
      bfr[jt] = *(const h8*)&bufB[p * 128 + cs];
    }
#pragma unroll
    for (int i2 = 0; i2 < 2; i2++)
#pragma unroll
      for (int jt = 0; jt < 4; jt++)
        acc3[i2][jt] = __builtin_amdgcn_mfma_f32_16x16x32_f16(
            a[i2], bfr[jt], acc3[i2][jt], 0, 0, 0);
  }

#pragma unroll
  for (int i2 = 0; i2 < 2; i2++) {
    int o = o0 + i2 * 16 + lh * 4;
    f4 bv = *(const f4*)&lbias[o];
#pragma unroll
    for (int jt = 0; jt < 4; jt++) {
      int t = t0 + jt * 16 + l15;
      f4 v = acc3[i2][jt];
      float4 sv = make_float4(v[0] + bv[0], v[1] + bv[1], v[2] + bv[2], v[3] + bv[3]);
      *(float4*)&outp[((size_t)n * TLEN + t) * CCH + o] = sv;
    }
  }
}

// ---------------------------------------------------------------------------
extern "C" void kernel_launch(void* const* d_in, const int* in_sizes, int n_in,
                              void* d_out, int out_size, void* d_ws, size_t ws_size,
                              hipStream_t stream) {
  const float* x  = (const float*)d_in[0];
  const float* r  = (const float*)d_in[1];
  // d_in[2] = f_out_same_in_size (==1)
  const float* w1 = (const float*)d_in[3];
  const float* b1 = (const float*)d_in[4];
  const float* w2 = (const float*)d_in[5];
  const float* b2 = (const float*)d_in[6];
  const float* fW = (const float*)d_in[7];
  const float* fb = (const float*)d_in[8];
  const float* lb = (const float*)d_in[9];
  const float* lw = (const float*)d_in[10];
  const float* lbias = (const float*)d_in[11];
  float* out = (float*)d_out;

  _Float16* h0    = (_Float16*)d_ws;        // 2,097,152 halves
  _Float16* h1    = h0 + 2097152;           // 2,097,152
  _Float16* Wsh   = h1 + 2097152;           // 393,216
  _Float16* linWh = Wsh + 393216;           // 16,384
  _Float16* Wg    = linWh + 16384;          // 1,572,864
  float*    fblb2 = (float*)(Wg + 1572864); // 98,304 floats

  k_init<<<1024, 256, 0, stream>>>(x, w1, w2, lw, fb, lb, h0, Wsh, linWh, fblb2);
  // gen (blocks 0..191) || pair1 (blocks 192..447)
  k_genpair<<<448, 256, 0, stream>>>(r, fW, fblb2, Wg, h0, h1, Wsh, b1, b2);
  // fused pair2+pair4: h1 -> h0
  k_pair24<<<dim3(16, 16), 256, 0, stream>>>(h1, h0, Wsh, b1, b2);
  // fused group chain: conv8 -> conv16 -> conv32 -> linear
  k_group<<<dim3(16, 16), 256, 0, stream>>>(h0, out, Wg, linWh, lbias);
}

// Round 19
// 68.699 us; speedup vs baseline: 1.8024x; 1.0594x over previous
//
#include <hip/hip_runtime.h>

// Problem constants
#define NB    16
#define TLEN  1024
#define CCH   128
#define DR    320

typedef _Float16 h8 __attribute__((ext_vector_type(8)));
typedef _Float16 h4 __attribute__((ext_vector_type(4)));
typedef _Float16 h2 __attribute__((ext_vector_type(2)));
typedef float    f4 __attribute__((ext_vector_type(4)));

// async global->LDS, 16 B/lane. LDS dest = readfirstlane(base)+lane*16, LINEAR.
__device__ __forceinline__ void gload16h(const _Float16* g, _Float16* l) {
  __builtin_amdgcn_global_load_lds(
      (const __attribute__((address_space(1))) void*)g,
      (__attribute__((address_space(3))) void*)l, 16, 0, 0);
}
__device__ __forceinline__ void gload16f(const float* g, float* l) {
  __builtin_amdgcn_global_load_lds(
      (const __attribute__((address_space(1))) void*)g,
      (__attribute__((address_space(3))) void*)l, 16, 0, 0);
}

// ---------------------------------------------------------------------------
// Init: cast x->h0 (f16), weight prep, fblb2 = fb+lb. (verified)
__global__ __launch_bounds__(256) void k_init(const float* __restrict__ x,
                                              const float* __restrict__ w1,
                                              const float* __restrict__ w2,
                                              const float* __restrict__ linw,
                                              const float* __restrict__ fb,
                                              const float* __restrict__ lb,
                                              _Float16* __restrict__ h0,
                                              _Float16* __restrict__ Wsh,
                                              _Float16* __restrict__ linWh,
                                              float* __restrict__ fblb2) {
  int i = blockIdx.x * 256 + threadIdx.x;     // 0..262143
  const float4* src = (const float4*)x + (size_t)i * 2;
  float4 a = src[0], b = src[1];
  h8 v;
  v[0] = (_Float16)a.x; v[1] = (_Float16)a.y; v[2] = (_Float16)a.z; v[3] = (_Float16)a.w;
  v[4] = (_Float16)b.x; v[5] = (_Float16)b.y; v[6] = (_Float16)b.z; v[7] = (_Float16)b.w;
  *(h8*)(h0 + (size_t)i * 8) = v;

  if (i < 6 * 32768) {
    int c = i & 127, k = (i >> 7) & 1, o = (i >> 8) & 127, i3 = i >> 15;
    const float* srcw = (i3 < 3) ? (w1 + i3 * 32768) : (w2 + (i3 - 3) * 32768);
    Wsh[i] = (_Float16)srcw[(o * 128 + c) * 2 + k];
  }
  if (i < 16384) linWh[i] = (_Float16)linw[i];
  if (i < 98304) fblb2[i] = fb[i] + lb[i];
}

// ---------------------------------------------------------------------------
struct SGen {
  float buf[3][32 * DR];    // 122,880 B
  float csc[4][16][16];     // 4,096 B
  float fbl[512];           // 2,048 B
};
struct SPair {              // sized for the LARGEST D used (D=4: RIN=84)
  _Float16 hin[84 * 128];
  _Float16 a[80 * 128];
};
union alignas(16) SU { SGen g; SPair p; };

// ---------------------------------------------------------------------------
// gen body — r14/r15 structure; B2 wait corrected to vmcnt(22) (stores count
// toward vmcnt: newest 22 = P(j+3)10 + S(j)1 + P(j+2)10 + S(j-1)1, so this
// drains exactly tile j+1 and older — true 2-deep pipeline).
__device__ __forceinline__ void gen_body(SGen& S, int bid, int tid,
                                         const float* __restrict__ r,
                                         const float* __restrict__ fW,
                                         const float* __restrict__ fblb2,
                                         _Float16* __restrict__ wg) {
  constexpr int NT = 16;
  const size_t rbase = (size_t)bid * 512;

  const int l = tid & 63, w = tid >> 6;
  const int l15 = l & 15, lh = l >> 4;
  const int rt = w >> 1, kh = w & 1;

  f4 rx[5], ry[5];
  const float* rp = r + l15 * DR + kh * 160 + lh * 8;
#pragma unroll
  for (int cb = 0; cb < 5; cb++) {
    rx[cb] = *(const f4*)(rp + cb * 32);
    ry[cb] = *(const f4*)(rp + cb * 32 + 4);
  }
  if (tid < 128) gload16f(fblb2 + rbase + tid * 4, S.fbl + tid * 4);
#pragma unroll
  for (int t = 0; t < 3; t++) {
    const float* s = fW + (rbase + (size_t)t * 32) * DR;
#pragma unroll
    for (int i = 0; i < 10; i++) {
      int f = tid + i * 256;
      gload16f(s + (size_t)f * 4, (float*)S.buf[t] + (size_t)f * 4);
    }
  }
  h8 bfr[5];
#pragma unroll
  for (int cb = 0; cb < 5; cb++) {
    h8 v;
    v[0] = (_Float16)rx[cb][0]; v[1] = (_Float16)rx[cb][1];
    v[2] = (_Float16)rx[cb][2]; v[3] = (_Float16)rx[cb][3];
    v[4] = (_Float16)ry[cb][0]; v[5] = (_Float16)ry[cb][1];
    v[6] = (_Float16)ry[cb][2]; v[7] = (_Float16)ry[cb][3];
    bfr[cb] = v;
  }
  asm volatile("s_waitcnt vmcnt(20) lgkmcnt(0)" ::: "memory");
  __builtin_amdgcn_s_barrier();
  __builtin_amdgcn_sched_barrier(0);

  const int rn = tid >> 4, rk = (tid >> 3) & 1, rcq = tid & 7;

  for (int j = 0; j < NT; j++) {
    const float* bp = (const float*)S.buf[j % 3];
    f4 acc = {0.f, 0.f, 0.f, 0.f};
    const float* arow = bp + (rt * 16 + l15) * DR + kh * 160 + lh * 8;
#pragma unroll
    for (int cb = 0; cb < 5; cb++) {
      f4 x = *(const f4*)(arow + cb * 32);
      f4 y = *(const f4*)(arow + cb * 32 + 4);
      h8 a;
      a[0] = (_Float16)x[0]; a[1] = (_Float16)x[1];
      a[2] = (_Float16)x[2]; a[3] = (_Float16)x[3];
      a[4] = (_Float16)y[0]; a[5] = (_Float16)y[1];
      a[6] = (_Float16)y[2]; a[7] = (_Float16)y[3];
      acc = __builtin_amdgcn_mfma_f32_16x16x32_f16(a, bfr[cb], acc, 0, 0, 0);
    }
#pragma unroll
    for (int rr = 0; rr < 4; rr++) S.csc[w][lh * 4 + rr][l15] = acc[rr];

    asm volatile("s_waitcnt lgkmcnt(0)" ::: "memory");
    __builtin_amdgcn_s_barrier();
    __builtin_amdgcn_sched_barrier(0);

    {
      const unsigned g32 = (unsigned)(rbase + (size_t)j * 32);
      const unsigned G = g32 >> 15, o = (g32 >> 8) & 127u, c0 = (g32 & 255u) >> 1;
      h2 v2;
#pragma unroll
      for (int i = 0; i < 2; i++) {
        int rl32 = (rcq * 2 + i) * 2 + rk;
        int hp = (rl32 >> 4) * 2, rr2 = rl32 & 15;
        float s = S.csc[hp][rr2][rn] + S.csc[hp + 1][rr2][rn] + S.fbl[j * 32 + rl32];
        v2[i] = (_Float16)s;
      }
      unsigned q = 3u * (unsigned)rn + G;
      *(h2*)&wg[(((size_t)q * 128 + o) * 2 + rk) * 128 + c0 + rcq * 2] = v2;
    }
    __builtin_amdgcn_sched_barrier(0);

    if (j + 3 < NT) {
      float* dstb = (float*)S.buf[j % 3];
      const float* src = fW + (rbase + (size_t)(j + 3) * 32) * DR;
#pragma unroll
      for (int i = 0; i < 10; i++) {
        int f = tid + i * 256;
        gload16f(src + (size_t)f * 4, dstb + (size_t)f * 4);
      }
    }

    if (j + 4 <= NT)
      asm volatile("s_waitcnt vmcnt(22) lgkmcnt(0)" ::: "memory");
    else if (j + 3 == NT)
      asm volatile("s_waitcnt vmcnt(12) lgkmcnt(0)" ::: "memory");
    else
      asm volatile("s_waitcnt vmcnt(0) lgkmcnt(0)" ::: "memory");
    __builtin_amdgcn_s_barrier();
    __builtin_amdgcn_sched_barrier(0);
  }
}

// ---------------------------------------------------------------------------
// pair body (verified r14/r15), on (tx, n).
template <int D>
__device__ __forceinline__ void pair_body(SPair& S, int tx, int n, int tid,
                                          const _Float16* in, _Float16* out,
                                          const _Float16* w1p, const _Float16* w2p,
                                          const float* b1p, const float* b2p) {
  constexpr int HA = 16;
  constexpr int HI = HA + D;
  constexpr int RIN = 80 + D;
  static_assert(RIN * 128 <= sizeof(SPair::hin) / sizeof(_Float16), "hin size");
  _Float16* hin_l = S.hin;
  _Float16* a_l = S.a;
  const int t0 = tx * 64;
  const _Float16* inN = in + (size_t)n * (TLEN * CCH);

  if (tx == 0) {
    for (int f = tid; f < HI * 16; f += 256)
      *(int4*)(hin_l + (size_t)f * 8) = make_int4(0, 0, 0, 0);
    for (int f = HI * 16 + tid; f < RIN * 16; f += 256) {
      int p = f >> 4, l16 = f & 15;
      int c8 = (l16 ^ (p & 15)) << 3;
      gload16h(inN + (t0 - HI + p) * 128 + c8, hin_l + f * 8);
    }
  } else {
    for (int f = tid; f < RIN * 16; f += 256) {
      int p = f >> 4, l16 = f & 15;
      int c8 = (l16 ^ (p & 15)) << 3;
      gload16h(inN + (t0 - HI + p) * 128 + c8, hin_l + f * 8);
    }
  }
  __syncthreads();

  const int l = tid & 63, w = tid >> 6;
  const int l15 = l & 15, lh = l >> 4;
  const int o0 = w * 32;

  f4 acc1[2][5] = {};
#pragma unroll
  for (int tap = 0; tap < 2; tap++) {
#pragma unroll
    for (int cb = 0; cb < 4; cb++) {
      const int c0 = cb * 32 + lh * 8;
      h8 a[2], bfr[5];
#pragma unroll
      for (int i2 = 0; i2 < 2; i2++) {
        int o = o0 + i2 * 16 + l15;
        a[i2] = *(const h8*)&w1p[(o * 2 + tap) * 128 + c0];
      }
#pragma unroll
      for (int jt = 0; jt < 5; jt++) {
        int p = jt * 16 + l15 + tap * D;
        int cs = c0 ^ ((p & 15) << 3);
        bfr[jt] = *(const h8*)&hin_l[p * 128 + cs];
      }
#pragma unroll
      for (int i2 = 0; i2 < 2; i2++)
#pragma unroll
        for (int jt = 0; jt < 5; jt++)
          acc1[i2][jt] = __builtin_amdgcn_mfma_f32_16x16x32_f16(
              a[i2], bfr[jt], acc1[i2][jt], 0, 0, 0);
    }
  }
#pragma unroll
  for (int i2 = 0; i2 < 2; i2++) {
    f4 bv = *(const f4*)&b1p[o0 + i2 * 16 + lh * 4];
    const int base8 = o0 + i2 * 16 + (lh >> 1) * 8;
    const int sub = (lh & 1) * 4;
#pragma unroll
    for (int jt = 0; jt < 5; jt++) {
      int p = jt * 16 + l15;
      h4 sv;
      if (tx == 0 && jt == 0) {
        sv[0] = sv[1] = sv[2] = sv[3] = (_Float16)0.f;
      } else {
        f4 v = acc1[i2][jt];
#pragma unroll
        for (int rr = 0; rr < 4; rr++) sv[rr] = (_Float16)fmaxf(v[rr] + bv[rr], 0.f);
      }
      *(h4*)&a_l[p * 128 + (base8 ^ ((p & 15) << 3)) + sub] = sv;
    }
  }
  __syncthreads();

  f4 acc2[2][4] = {};
#pragma unroll
  for (int tap = 0; tap < 2; tap++) {
#pragma unroll
    for (int cb = 0; cb < 4; cb++) {
      const int c0 = cb * 32 + lh * 8;
      h8 a[2], bfr[4];
#pragma unroll
      for (int i2 = 0; i2 < 2; i2++) {
        int o = o0 + i2 * 16 + l15;
        a[i2] = *(const h8*)&w2p[(o * 2 + tap) * 128 + c0];
      }
#pragma unroll
      for (int jt = 0; jt < 4; jt++) {
        int pa = jt * 16 + l15 + (HA - D) + tap * D;
        int cs = c0 ^ ((pa & 15) << 3);
        bfr[jt] = *(const h8*)&a_l[pa * 128 + cs];
      }
#pragma unroll
      for (int i2 = 0; i2 < 2; i2++)
#pragma unroll
        for (int jt = 0; jt < 4; jt++)
          acc2[i2][jt] = __builtin_amdgcn_mfma_f32_16x16x32_f16(
              a[i2], bfr[jt], acc2[i2][jt], 0, 0, 0);
    }
  }

  _Float16* outN = out + (size_t)n * (TLEN * CCH);
#pragma unroll
  for (int i2 = 0; i2 < 2; i2++) {
    f4 bv = *(const f4*)&b2p[o0 + i2 * 16 + lh * 4];
    const int base8 = o0 + i2 * 16 + (lh >> 1) * 8;
    const int sub = (lh & 1) * 4;
#pragma unroll
    for (int jt = 0; jt < 4; jt++) {
      int t = t0 + jt * 16 + l15;
      int pr = jt * 16 + l15 + HA + D;
      h4 rv = *(const h4*)&hin_l[pr * 128 + (base8 ^ ((pr & 15) << 3)) + sub];
      f4 v = acc2[i2][jt];
      h4 sv;
#pragma unroll
      for (int rr = 0; rr < 4; rr++) {
        float z = fmaxf(v[rr] + bv[rr], 0.f);
        sv[rr] = (_Float16)fmaxf(z + (float)rv[rr], 0.f);
      }
      *(h4*)&outN[t * 128 + o0 + i2 * 16 + lh * 4] = sv;
    }
  }
}

// ---------------------------------------------------------------------------
// Fused gen || pair1 (post-timing verified): grid 448.
__global__ __launch_bounds__(256, 1) void k_genpair(
    const float* __restrict__ r, const float* __restrict__ fW,
    const float* __restrict__ fblb2, _Float16* __restrict__ wg,
    const _Float16* __restrict__ h0, _Float16* __restrict__ h1,
    const _Float16* __restrict__ Wsh,
    const float* __restrict__ b1, const float* __restrict__ b2) {
  __shared__ SU su;
  const int bid = blockIdx.x, tid = threadIdx.x;
  if (bid < 192) {
    gen_body(su.g, bid, tid, r, fW, fblb2, wg);
  } else {
    int q = bid - 192;
    pair_body<1>(su.p, q & 15, q >> 4, tid, h0, h1,
                 Wsh, Wsh + 3 * 32768, b1, b2);
  }
}

// ---------------------------------------------------------------------------
// Generalized pair stage on LDS (verified r18 incl. post-timing).
template <int D, int NJ, bool GOUT>
__device__ __forceinline__ void pstage(const _Float16* __restrict__ w1p,
                                       const _Float16* __restrict__ w2p,
                                       const float* __restrict__ b1p,
                                       const float* __restrict__ b2p,
                                       const _Float16* __restrict__ inb,
                                       _Float16* __restrict__ ab,
                                       _Float16* __restrict__ outb,
                                       _Float16* __restrict__ goutN, int t0,
                                       int zlimA, int zlimO, int tid) {
  constexpr int NA = NJ + 1;
  const int l = tid & 63, w = tid >> 6;
  const int l15 = l & 15, lh = l >> 4;
  const int o0 = w * 32;
  const int base8 = o0 + (lh >> 1) * 8;
  const int sub = (lh & 1) * 4;

  f4 acc1[2][NA] = {};
#pragma unroll
  for (int tap = 0; tap < 2; tap++) {
#pragma unroll
    for (int cb = 0; cb < 4; cb++) {
      const int c0 = cb * 32 + lh * 8;
      h8 a[2], bfr[NA];
#pragma unroll
      for (int i2 = 0; i2 < 2; i2++) {
        int o = o0 + i2 * 16 + l15;
        a[i2] = *(const h8*)&w1p[(o * 2 + tap) * 128 + c0];
      }
#pragma unroll
      for (int jt = 0; jt < NA; jt++) {
        int p = jt * 16 + l15 + tap * D;
        int cs = c0 ^ ((p & 15) << 3);
        bfr[jt] = *(const h8*)&inb[p * 128 + cs];
      }
#pragma unroll
      for (int i2 = 0; i2 < 2; i2++)
#pragma unroll
        for (int jt = 0; jt < NA; jt++)
          acc1[i2][jt] = __builtin_amdgcn_mfma_f32_16x16x32_f16(
              a[i2], bfr[jt], acc1[i2][jt], 0, 0, 0);
    }
  }
#pragma unroll
  for (int i2 = 0; i2 < 2; i2++) {
    f4 bv = *(const f4*)&b1p[o0 + i2 * 16 + lh * 4];
    const int b8 = base8 + i2 * 16;
#pragma unroll
    for (int jt = 0; jt < NA; jt++) {
      int q = jt * 16 + l15;
      h4 sv;
      if (q < zlimA) {
        sv[0] = sv[1] = sv[2] = sv[3] = (_Float16)0.f;
      } else {
        f4 v = acc1[i2][jt];
#pragma unroll
        for (int rr = 0; rr < 4; rr++) sv[rr] = (_Float16)fmaxf(v[rr] + bv[rr], 0.f);
      }
      *(h4*)&ab[q * 128 + (b8 ^ ((q & 15) << 3)) + sub] = sv;
    }
  }
  __syncthreads();

  f4 acc2[2][NJ] = {};
#pragma unroll
  for (int tap = 0; tap < 2; tap++) {
#pragma unroll
    for (int cb = 0; cb < 4; cb++) {
      const int c0 = cb * 32 + lh * 8;
      h8 a[2], bfr[NJ];
#pragma unroll
      for (int i2 = 0; i2 < 2; i2++) {
        int o = o0 + i2 * 16 + l15;
        a[i2] = *(const h8*)&w2p[(o * 2 + tap) * 128 + c0];
      }
#pragma unroll
      for (int jt = 0; jt < NJ; jt++) {
        int pa = jt * 16 + l15 + (16 - 2 * D) + tap * D;
        int cs = c0 ^ ((pa & 15) << 3);
        bfr[jt] = *(const h8*)&ab[pa * 128 + cs];
      }
#pragma unroll
      for (int i2 = 0; i2 < 2; i2++)
#pragma unroll
        for (int jt = 0; jt < NJ; jt++)
          acc2[i2][jt] = __builtin_amdgcn_mfma_f32_16x16x32_f16(
              a[i2], bfr[jt], acc2[i2][jt], 0, 0, 0);
    }
  }
#pragma unroll
  for (int i2 = 0; i2 < 2; i2++) {
    f4 bv = *(const f4*)&b2p[o0 + i2 * 16 + lh * 4];
    const int b8 = base8 + i2 * 16;
#pragma unroll
    for (int jt = 0; jt < NJ; jt++) {
      int r = jt * 16 + l15;
      int pr = r + 16;
      h4 sv;
      if (r < zlimO) {
        sv[0] = sv[1] = sv[2] = sv[3] = (_Float16)0.f;
      } else {
        h4 rv = *(const h4*)&inb[pr * 128 + (b8 ^ ((pr & 15) << 3)) + sub];
        f4 v = acc2[i2][jt];
#pragma unroll
        for (int rr = 0; rr < 4; rr++) {
          float z = fmaxf(v[rr] + bv[rr], 0.f);
          sv[rr] = (_Float16)fmaxf(z + (float)rv[rr], 0.f);
        }
      }
      if (GOUT) {
        int t = t0 + r;
        *(h4*)&goutN[t * 128 + o0 + i2 * 16 + lh * 4] = sv;
      } else {
        *(h4*)&outb[r * 128 + (b8 ^ (l15 << 3)) + sub] = sv;
      }
    }
  }
}

// ---------------------------------------------------------------------------
// Fused pair2 + pair4 via halo recompute (verified r18 incl. post-timing).
__global__ __launch_bounds__(256) void k_pair24(const _Float16* __restrict__ in,
                                                _Float16* __restrict__ out,
                                                const _Float16* __restrict__ Wsh,
                                                const float* __restrict__ b1,
                                                const float* __restrict__ b2) {
  __shared__ _Float16 B0[104 * 128];
  __shared__ _Float16 B1[96 * 128];
  __shared__ _Float16 B2[88 * 128];
  const int tid = threadIdx.x;
  const int tx = blockIdx.x, n = blockIdx.y;
  const int t0 = tx * 64;
  const _Float16* inN = in + (size_t)n * (TLEN * CCH);

  for (int f = 96 * 16 + tid; f < 104 * 16; f += 256)
    *(int4*)(B0 + (size_t)f * 8) = make_int4(0, 0, 0, 0);
  for (int f = 80 * 16 + tid; f < 88 * 16; f += 256)
    *(int4*)(B2 + (size_t)f * 8) = make_int4(0, 0, 0, 0);

  if (tx == 0) {
    for (int f = tid; f < 32 * 16; f += 256)
      *(int4*)(B0 + (size_t)f * 8) = make_int4(0, 0, 0, 0);
    for (int f = 32 * 16 + tid; f < 96 * 16; f += 256) {
      int p = f >> 4, l16 = f & 15;
      int c8 = (l16 ^ (p & 15)) << 3;
      gload16h(inN + (t0 - 32 + p) * 128 + c8, B0 + f * 8);
    }
  } else {
    for (int f = tid; f < 96 * 16; f += 256) {
      int p = f >> 4, l16 = f & 15;
      int c8 = (l16 ^ (p & 15)) << 3;
      gload16h(inN + (t0 - 32 + p) * 128 + c8, B0 + f * 8);
    }
  }
  __syncthreads();

  pstage<2, 5, false>(Wsh + 1 * 32768, Wsh + 4 * 32768, b1 + 128, b2 + 128,
                      B0, B1, B2, nullptr, t0,
                      (tx == 0) ? 30 : 0, (tx == 0) ? 16 : 0, tid);
  __syncthreads();
  pstage<4, 4, true>(Wsh + 2 * 32768, Wsh + 5 * 32768, b1 + 256, b2 + 256,
                     B2, B1, nullptr,
                     out + (size_t)n * (TLEN * CCH), t0,
                     (tx == 0) ? 12 : 0, 0, tid);
}

// ---------------------------------------------------------------------------
// One group-conv stage on LDS buffers (verified r15).
template <int D, int NJ>
__device__ __forceinline__ void gstage(const _Float16* __restrict__ Wl,
                                       const _Float16* __restrict__ inb,
                                       _Float16* __restrict__ outb,
                                       int zlim, int tid) {
  const int l = tid & 63, w = tid >> 6;
  const int l15 = l & 15, lh = l >> 4;
  const int o0 = w * 32;
  f4 acc[2][NJ] = {};

#pragma unroll
  for (int tap = 0; tap < 2; tap++) {
#pragma unroll
    for (int cb = 0; cb < 4; cb++) {
      const int c0 = cb * 32 + 8 * lh;
      h8 a[2], bfr[NJ];
#pragma unroll
      for (int i2 = 0; i2 < 2; i2++) {
        int o = o0 + i2 * 16 + l15;
        int cs = c0 ^ ((o & 15) << 3);
        a[i2] = *(const h8*)&Wl[(o * 2 + tap) * 128 + cs];
      }
#pragma unroll
      for (int jt = 0; jt < NJ; jt++) {
        int p = jt * 16 + l15 + tap * D;
        int cs = c0 ^ ((p & 15) << 3);
        bfr[jt] = *(const h8*)&inb[p * 128 + cs];
      }
#pragma unroll
      for (int i2 = 0; i2 < 2; i2++)
#pragma unroll
        for (int jt = 0; jt < NJ; jt++)
          acc[i2][jt] = __builtin_amdgcn_mfma_f32_16x16x32_f16(
              a[i2], bfr[jt], acc[i2][jt], 0, 0, 0);
    }
  }

#pragma unroll
  for (int i2 = 0; i2 < 2; i2++) {
    const int base8 = o0 + i2 * 16 + (lh >> 1) * 8;
    const int sub = (lh & 1) * 4;
#pragma unroll
    for (int jt = 0; jt < NJ; jt++) {
      int rrow = jt * 16 + l15;
      int pr = rrow + D;
      h4 sv;
      if (rrow < zlim) {
        sv[0] = sv[1] = sv[2] = sv[3] = (_Float16)0.f;
      } else {
        h4 rv = *(const h4*)&inb[pr * 128 + (base8 ^ ((pr & 15) << 3)) + sub];
        f4 v = acc[i2][jt];
#pragma unroll
        for (int rr = 0; rr < 4; rr++) {
          float z = fmaxf(v[rr], 0.f);
          sv[rr] = (_Float16)fmaxf(z + (float)rv[rr], 0.f);
        }
      }
      *(h4*)&outb[rrow * 128 + (base8 ^ (l15 << 3)) + sub] = sv;
    }
  }
}

// ---------------------------------------------------------------------------
// Fused group chain (verified r15/r18) with XCD-aware block decode:
// 1-D grid 256; n = (bid&7)|(((bid>>3)&1)<<3), tx = bid>>4 -> all 16 blocks
// of a given n satisfy bid % 8 == n % 8 (one XCD L2 per n's Wg slice).
__global__ __launch_bounds__(256, 1) void k_group(const _Float16* __restrict__ in,
                                                  float* __restrict__ outp,
                                                  const _Float16* __restrict__ wg,
                                                  const _Float16* __restrict__ linWh,
                                                  const float* __restrict__ lbias) {
  __shared__ _Float16 bufA[120 * 128];
  __shared__ _Float16 bufB[112 * 128];
  __shared__ _Float16 Wl[256 * 128];
  const int tid = threadIdx.x;
  const int bid = blockIdx.x;
  const int n = (bid & 7) | (((bid >> 3) & 1) << 3);
  const int tx = bid >> 4;
  const int t0 = tx * 64;
  const _Float16* inN = in + (size_t)n * (TLEN * CCH);
  const _Float16* wp1 = wg + (size_t)n * 32768;
  const _Float16* wp2 = wg + 524288 + (size_t)n * 32768;
  const _Float16* wp3 = wg + 1048576 + (size_t)n * 32768;

  if (tx == 0) {
    for (int f = tid; f < 56 * 16; f += 256)
      *(int4*)(bufA + (size_t)f * 8) = make_int4(0, 0, 0, 0);
    for (int f = 56 * 16 + tid; f < 120 * 16; f += 256) {
      int p = f >> 4, l16 = f & 15;
      int c8 = (l16 ^ (p & 15)) << 3;
      gload16h(inN + (t0 - 56 + p) * 128 + c8, bufA + f * 8);
    }
  } else {
    for (int f = tid; f < 120 * 16; f += 256) {
      int p = f >> 4, l16 = f & 15;
      int c8 = (l16 ^ (p & 15)) << 3;
      gload16h(inN + (t0 - 56 + p) * 128 + c8, bufA + f * 8);
    }
  }
  for (int f = tid; f < 4096; f += 256) {
    int row = f >> 4, l16 = f & 15;
    int c8 = (l16 ^ ((row >> 1) & 15)) << 3;
    gload16h(wp1 + row * 128 + c8, Wl + f * 8);
  }
  __syncthreads();

  gstage<8, 7>(Wl, bufA, bufB, (tx == 0) ? 48 : 0, tid);
  __syncthreads();
  for (int f = tid; f < 4096; f += 256) {
    int row = f >> 4, l16 = f & 15;
    int c8 = (l16 ^ ((row >> 1) & 15)) << 3;
    gload16h(wp2 + row * 128 + c8, Wl + f * 8);
  }
  __syncthreads();

  gstage<16, 6>(Wl, bufB, bufA, (tx == 0) ? 32 : 0, tid);
  __syncthreads();
  for (int f = tid; f < 4096; f += 256) {
    int row = f >> 4, l16 = f & 15;
    int c8 = (l16 ^ ((row >> 1) & 15)) << 3;
    gload16h(wp3 + row * 128 + c8, Wl + f * 8);
  }
  __syncthreads();

  gstage<32, 4>(Wl, bufA, bufB, 0, tid);
  __syncthreads();

  const int l = tid & 63, w = tid >> 6;
  const int l15 = l & 15, lh = l >> 4;
  const int o0 = w * 32;
  f4 acc3[2][4] = {};
#pragma unroll
  for (int cb = 0; cb < 4; cb++) {
    const int c0 = cb * 32 + lh * 8;
    h8 a[2], bfr[4];
#pragma unroll
    for (int i2 = 0; i2 < 2; i2++) {
      int o = o0 + i2 * 16 + l15;
      a[i2] = *(const h8*)&linWh[o * 128 + c0];
    }
#pragma unroll
    for (int jt = 0; jt < 4; jt++) {
      int p = jt * 16 + l15;
      int cs = c0 ^ ((p & 15) << 3);
      bfr[jt] = *(const h8*)&bufB[p * 128 + cs];
    }
#pragma unroll
    for (int i2 = 0; i2 < 2; i2++)
#pragma unroll
      for (int jt = 0; jt < 4; jt++)
        acc3[i2][jt] = __builtin_amdgcn_mfma_f32_16x16x32_f16(
            a[i2], bfr[jt], acc3[i2][jt], 0, 0, 0);
  }

#pragma unroll
  for (int i2 = 0; i2 < 2; i2++) {
    int o = o0 + i2 * 16 + lh * 4;
    f4 bv = *(const f4*)&lbias[o];
#pragma unroll
    for (int jt = 0; jt < 4; jt++) {
      int t = t0 + jt * 16 + l15;
      f4 v = acc3[i2][jt];
      float4 sv = make_float4(v[0] + bv[0], v[1] + bv[1], v[2] + bv[2], v[3] + bv[3]);
      *(float4*)&outp[((size_t)n * TLEN + t) * CCH + o] = sv;
    }
  }
}

// ---------------------------------------------------------------------------
extern "C" void kernel_launch(void* const* d_in, const int* in_sizes, int n_in,
                              void* d_out, int out_size, void* d_ws, size_t ws_size,
                              hipStream_t stream) {
  const float* x  = (const float*)d_in[0];
  const float* r  = (const float*)d_in[1];
  // d_in[2] = f_out_same_in_size (==1)
  const float* w1 = (const float*)d_in[3];
  const float* b1 = (const float*)d_in[4];
  const float* w2 = (const float*)d_in[5];
  const float* b2 = (const float*)d_in[6];
  const float* fW = (const float*)d_in[7];
  const float* fb = (const float*)d_in[8];
  const float* lb = (const float*)d_in[9];
  const float* lw = (const float*)d_in[10];
  const float* lbias = (const float*)d_in[11];
  float* out = (float*)d_out;

  _Float16* h0    = (_Float16*)d_ws;        // 2,097,152 halves
  _Float16* h1    = h0 + 2097152;           // 2,097,152
  _Float16* Wsh   = h1 + 2097152;           // 393,216
  _Float16* linWh = Wsh + 393216;           // 16,384
  _Float16* Wg    = linWh + 16384;          // 1,572,864
  float*    fblb2 = (float*)(Wg + 1572864); // 98,304 floats

  k_init<<<1024, 256, 0, stream>>>(x, w1, w2, lw, fb, lb, h0, Wsh, linWh, fblb2);
  // gen (blocks 0..191) || pair1 (blocks 192..447)
  k_genpair<<<448, 256, 0, stream>>>(r, fW, fblb2, Wg, h0, h1, Wsh, b1, b2);
  // fused pair2+pair4: h1 -> h0
  k_pair24<<<dim3(16, 16), 256, 0, stream>>>(h1, h0, Wsh, b1, b2);
  // fused group chain (XCD-aware 1-D grid): conv8 -> conv16 -> conv32 -> linear
  k_group<<<256, 256, 0, stream>>>(h0, out, Wg, linWh, lbias);
}